// Round 13
// baseline (155.847 us; speedup 1.0000x reference)
//
#include <hip/hip_runtime.h>
#include <hip/hip_bf16.h>

#define B_ 8
#define T_ 2048
#define D_ 256
#define H_ 128

typedef float f32x4 __attribute__((ext_vector_type(4)));
typedef short bf16x8 __attribute__((ext_vector_type(8)));
typedef unsigned short u16x8 __attribute__((ext_vector_type(8)));

__device__ __forceinline__ unsigned short f2bf(float f){
  union { float f; unsigned u; } v; v.f = f;
  unsigned u = v.u;
  unsigned r = (u + 0x7FFFu + ((u >> 16) & 1u)) >> 16;
  return (unsigned short)r;
}

__device__ __forceinline__ float bf2f(unsigned short us){
  union { unsigned u; float f; } v; v.u = ((unsigned)us) << 16; return v.f;
}

// 256-thread (4-wave) block reduce; sbuf must be float[4]
__device__ __forceinline__ float blk_reduce(float v, bool is_max, float* sbuf){
  for(int o = 32; o > 0; o >>= 1){
    float t = __shfl_xor(v, o);
    v = is_max ? fmaxf(v, t) : (v + t);
  }
  int w = threadIdx.x >> 6;
  __syncthreads();
  if((threadIdx.x & 63) == 0) sbuf[w] = v;
  __syncthreads();
  float r = sbuf[0];
  for(int i = 1; i < 4; i++) r = is_max ? fmaxf(r, sbuf[i]) : (r + sbuf[i]);
  return r;
}

// ---------------------------------------------------------------------------
// Kernel 1: QKV projection (R7-verified structure). grid (256 rowtiles, 3
// mats), 256 threads.
// ---------------------------------------------------------------------------
__global__ __launch_bounds__(256) void qkv_kernel(
    const float* __restrict__ x,
    const float* __restrict__ Wq, const float* __restrict__ bq,
    const float* __restrict__ Wk, const float* __restrict__ bk,
    const float* __restrict__ Wv, const float* __restrict__ bv,
    unsigned short* __restrict__ Qsigb, unsigned short* __restrict__ Ktb,
    unsigned short* __restrict__ Vtb)
{
  const int mat = blockIdx.y;
  const int g0  = blockIdx.x * 64;
  const int tid = threadIdx.x;
  const float* W   = (mat == 0) ? Wq : (mat == 1) ? Wk : Wv;
  const float* bia = (mat == 0) ? bq : (mat == 1) ? bk : bv;

  __shared__ __align__(16) short As[64 * 32];
  __shared__ __align__(16) short Ws[128 * 32];
  __shared__ float tbuf[64][129];

  const int w = tid >> 6, lane = tid & 63, rl = lane & 15, kg = lane >> 4;
  f32x4 acc[8];
  for(int i = 0; i < 8; i++) acc[i] = (f32x4){0.f, 0.f, 0.f, 0.f};

  const int c = tid & 31, r8 = tid >> 5;
  for(int kk = 0; kk < 256; kk += 32){
    __syncthreads();
    for(int p = 0; p < 8; p++){
      int rr = r8 + p * 8;
      As[rr * 32 + c] = (short)f2bf(x[(size_t)(g0 + rr) * 256 + kk + c]);
    }
    for(int p = 0; p < 16; p++){
      int hh = r8 + p * 8;
      Ws[hh * 32 + c] = (short)f2bf(W[(size_t)hh * 256 + kk + c]);
    }
    __syncthreads();
    bf16x8 a = *(const bf16x8*)&As[(w * 16 + rl) * 32 + kg * 8];
    for(int cf = 0; cf < 8; cf++){
      bf16x8 bb = *(const bf16x8*)&Ws[(cf * 16 + rl) * 32 + kg * 8];
      acc[cf] = __builtin_amdgcn_mfma_f32_16x16x32_bf16(a, bb, acc[cf], 0, 0, 0);
    }
  }

  const int b = g0 >> 11, t0 = g0 & 2047;
  if(mat == 0){
    for(int cf = 0; cf < 8; cf++){
      int h = cf * 16 + rl;
      float bh = bia[h];
      for(int r = 0; r < 4; r++){
        int tl = w * 16 + kg * 4 + r;
        float v = acc[cf][r] + bh;
        Qsigb[(size_t)(g0 + tl) * 128 + h] = f2bf(1.f / (1.f + __expf(-v)));
      }
    }
  } else {
    for(int cf = 0; cf < 8; cf++){
      int h = cf * 16 + rl;
      float bh = bia[h];
      for(int r = 0; r < 4; r++){
        int tl = w * 16 + kg * 4 + r;
        tbuf[tl][h] = acc[cf][r] + bh;
      }
    }
    __syncthreads();
    unsigned short* dst = (mat == 1) ? Ktb : Vtb;
    int h = tid >> 1, part = tid & 1;
    unsigned short* drow = dst + (size_t)(b * 128 + h) * 2048 + t0 + part * 32;
#pragma unroll
    for(int i = 0; i < 32; i += 8){
      u16x8 o;
#pragma unroll
      for(int j = 0; j < 8; j++) o[j] = f2bf(tbuf[part * 32 + i + j][h]);
      *(u16x8*)(drow + i) = o;
    }
  }
}

// ---------------------------------------------------------------------------
// Kernel 2: column softmax over time for K -> Mt rows 0..127 = bf16(eK*V),
// rows 128..255 = bf16(eK). Inputs bf16.
// ---------------------------------------------------------------------------
__global__ __launch_bounds__(256) void colsm_kernel(
    const unsigned short* __restrict__ Ktb, const unsigned short* __restrict__ Vtb,
    unsigned short* __restrict__ Mt)
{
  __shared__ float sbuf[4];
  const int b  = blockIdx.x >> 5;
  const int hg = blockIdx.x & 31;
  const int tid = threadIdx.x;
  for(int i = 0; i < 4; i++){
    int h = hg * 4 + i;
    const unsigned short* kr = Ktb + (size_t)(b * 128 + h) * 2048;
    const unsigned short* vr = Vtb + (size_t)(b * 128 + h) * 2048;
    u16x8 k8 = *(const u16x8*)(kr + tid * 8);
    u16x8 v8 = *(const u16x8*)(vr + tid * 8);
    float kf[8];
#pragma unroll
    for(int j = 0; j < 8; j++) kf[j] = bf2f(k8[j]);
    float m = kf[0];
#pragma unroll
    for(int j = 1; j < 8; j++) m = fmaxf(m, kf[j]);
    m = blk_reduce(m, true, sbuf);
    float s = 0.f;
#pragma unroll
    for(int j = 0; j < 8; j++) s += __expf(kf[j] - m);
    s = blk_reduce(s, false, sbuf);
    float iz = 1.f / s;
    u16x8 pv, pe;
#pragma unroll
    for(int j = 0; j < 8; j++){
      float e = __expf(__expf(kf[j] - m) * iz);
      pv[j] = f2bf(e * bf2f(v8[j]));
      pe[j] = f2bf(e);
    }
    *(u16x8*)(Mt + (size_t)(b * 256 + h) * 2048 + tid * 8) = pv;
    *(u16x8*)(Mt + (size_t)(b * 256 + 128 + h) * 2048 + tid * 8) = pe;
  }
}

// ---------------------------------------------------------------------------
// Kernel 3: fused row-softmax + exp -> bf16 eab. One row per block.
// Reads ab once (registers), at BW roofline (~201 MB).
// ---------------------------------------------------------------------------
__global__ __launch_bounds__(256) void softexp_kernel(
    const float* __restrict__ ab, unsigned short* __restrict__ eab)
{
  __shared__ float sbuf[4];
  const size_t row = blockIdx.x;
  const float* r = ab + row * 2048;
  const int tid = threadIdx.x;
  float4 v0 = *(const float4*)(r + tid * 4);
  float4 v1 = *(const float4*)(r + tid * 4 + 1024);
  float m = fmaxf(fmaxf(fmaxf(v0.x, v0.y), fmaxf(v0.z, v0.w)),
                  fmaxf(fmaxf(v1.x, v1.y), fmaxf(v1.z, v1.w)));
  m = blk_reduce(m, true, sbuf);
  float e0x = __expf(v0.x - m), e0y = __expf(v0.y - m);
  float e0z = __expf(v0.z - m), e0w = __expf(v0.w - m);
  float e1x = __expf(v1.x - m), e1y = __expf(v1.y - m);
  float e1z = __expf(v1.z - m), e1w = __expf(v1.w - m);
  float s = e0x + e0y + e0z + e0w + e1x + e1y + e1z + e1w;
  s = blk_reduce(s, false, sbuf);
  float iz = 1.f / s;
  ushort4 o;
  o.x = f2bf(__expf(e0x * iz)); o.y = f2bf(__expf(e0y * iz));
  o.z = f2bf(__expf(e0z * iz)); o.w = f2bf(__expf(e0w * iz));
  *(ushort4*)(eab + row * 2048 + tid * 4) = o;
  o.x = f2bf(__expf(e1x * iz)); o.y = f2bf(__expf(e1y * iz));
  o.z = f2bf(__expf(e1z * iz)); o.w = f2bf(__expf(e1w * iz));
  *(ushort4*)(eab + row * 2048 + tid * 4 + 1024) = o;
}

// ---------------------------------------------------------------------------
// Kernel 4: bf16 GEMM — barrier-free, LDS-free, all-register variant.
// Same decomposition/fragment algebra as the verified gemm4 (block 64 rows x
// (64 num + 64 den), wave-tile 32x64, grid 512 = 8 XCD-pinned batches x 32
// rt x 2 hb), but each wave gathers its A/B fragments directly from global
// into registers: 12 x dwordx4 per K-tile, double-banked depth-1 prefetch,
// NO s_barrier / LDS anywhere -> waves run phase-shifted and hide each
// other's load latency. Intra-block duplicate fragments served by L1
// (24 KB unique per K-step < 32 KB L1). __launch_bounds__(256,3): ~140 VGPR,
// 12 waves/CU.
// ---------------------------------------------------------------------------
__global__ __launch_bounds__(256, 3) void aft_gemm10(
    const unsigned short* __restrict__ eab,
    const unsigned short* __restrict__ Mt,
    const unsigned short* __restrict__ Qsigb,
    unsigned short* __restrict__ Yt)
{
  const int bid = blockIdx.x;
  const int b   = bid & 7;           // batch pinned to XCD
  const int idx = bid >> 3;          // 0..63
  const int rt  = idx >> 1;          // 0..31
  const int hb  = idx & 1;
  const int t0  = rt * 64;
  const int h0  = hb * 64;

  const int tid = threadIdx.x;
  const int w = tid >> 6, lane = tid & 63;
  const int rl = lane & 15, kg = lane >> 4;
  const int wr = w >> 1, wc = w & 1;

  const size_t rowbase = (size_t)b * 2048 + t0;

  // Per-lane fragment bases. A row = rowbase + wr*32 + {0,16} + rl.
  const unsigned short* a_base =
      eab + (rowbase + (size_t)(wr * 32 + rl)) * 2048 + kg * 8;
  // B row bases for cf = 0..3 (cf 0,1 = num cols, cf 2,3 = den cols).
  const unsigned short* b_base[4];
#pragma unroll
  for(int cf = 0; cf < 4; cf++){
    const int colbase = (cf < 2) ? (h0 + wc * 32 + cf * 16)
                                 : (128 + h0 + wc * 32 + (cf - 2) * 16);
    b_base[cf] = Mt + ((size_t)b * 256 + colbase + rl) * 2048 + kg * 8;
  }

  f32x4 acc[2][4];
#pragma unroll
  for(int i = 0; i < 2; i++)
#pragma unroll
    for(int j = 0; j < 4; j++) acc[i][j] = (f32x4){0.f, 0.f, 0.f, 0.f};

  // Load one K-tile (t) into a named bank: A[ks][rf], B[ks][cf].
  // Element k-range of frag (ks): k = ks*32 + kg*8 .. +8  (t*64 global).
  #define LOADT(AB, t) do { \
    _Pragma("unroll") \
    for(int ks = 0; ks < 2; ++ks){ \
      AB##A[ks][0] = *(const bf16x8*)(a_base + (t) * 64 + ks * 32); \
      AB##A[ks][1] = *(const bf16x8*)(a_base + 16 * 2048 + (t) * 64 + ks * 32); \
      _Pragma("unroll") \
      for(int cf = 0; cf < 4; ++cf) \
        AB##B[ks][cf] = *(const bf16x8*)(b_base[cf] + (t) * 64 + ks * 32); \
    } \
  } while(0)

  #define MM(AB) do { \
    _Pragma("unroll") \
    for(int ks = 0; ks < 2; ++ks) \
      _Pragma("unroll") \
      for(int cf = 0; cf < 4; ++cf){ \
        acc[0][cf] = __builtin_amdgcn_mfma_f32_16x16x32_bf16(AB##A[ks][0], AB##B[ks][cf], acc[0][cf], 0, 0, 0); \
        acc[1][cf] = __builtin_amdgcn_mfma_f32_16x16x32_bf16(AB##A[ks][1], AB##B[ks][cf], acc[1][cf], 0, 0, 0); \
      } \
  } while(0)

  bf16x8 XA[2][2], XB[2][4], YA[2][2], YB[2][4];
  LOADT(X, 0);
#pragma unroll 1
  for(int t = 0; t < 32; t += 2){
    LOADT(Y, t + 1);        // prefetch next tile while X computes
    MM(X);
    if(t + 2 < 32) LOADT(X, t + 2);
    MM(Y);
  }
  #undef LOADT
  #undef MM

#pragma unroll
  for(int rf = 0; rf < 2; ++rf)
#pragma unroll
    for(int cf = 0; cf < 2; ++cf){
      const int h = h0 + wc * 32 + cf * 16 + rl;
#pragma unroll
      for(int r = 0; r < 4; ++r){
        const int tl = wr * 32 + rf * 16 + kg * 4 + r;
        const size_t g = rowbase + tl;
        float num = acc[rf][cf][r], den = acc[rf][cf + 2][r];
        float q = bf2f(Qsigb[g * 128 + h]);
        Yt[g * 128 + h] = f2bf(q * num / den);
      }
    }
}

// ---------------------------------------------------------------------------
// Kernel 5: output projection out = Yt @ Wp^T + bp. grid = 256, 256 threads.
// ---------------------------------------------------------------------------
__global__ __launch_bounds__(256) void outproj_kernel(
    const unsigned short* __restrict__ Yt, const float* __restrict__ Wp,
    const float* __restrict__ bp, float* __restrict__ out)
{
  __shared__ __align__(16) short As[64 * 32];
  __shared__ __align__(16) short Bs[256 * 32];
  const int g0 = blockIdx.x * 64;
  const int tid = threadIdx.x;
  const int w = tid >> 6, lane = tid & 63, rl = lane & 15, kg = lane >> 4;
  f32x4 acc[16];
  for(int i = 0; i < 16; i++) acc[i] = (f32x4){0.f, 0.f, 0.f, 0.f};

  const int ar = tid >> 2, apart = tid & 3;
  const int c = tid & 31, dr = tid >> 5;
  for(int k = 0; k < 128; k += 32){
    __syncthreads();
    *(uint4*)&As[ar * 32 + apart * 8] =
        *(const uint4*)(Yt + (size_t)(g0 + ar) * 128 + k + apart * 8);
    for(int p = 0; p < 32; p++){
      int d = dr + p * 8;
      Bs[d * 32 + c] = (short)f2bf(Wp[(size_t)d * 128 + k + c]);
    }
    __syncthreads();
    bf16x8 a = *(const bf16x8*)&As[(w * 16 + rl) * 32 + kg * 8];
    for(int cf = 0; cf < 16; cf++){
      bf16x8 bb = *(const bf16x8*)&Bs[(cf * 16 + rl) * 32 + kg * 8];
      acc[cf] = __builtin_amdgcn_mfma_f32_16x16x32_bf16(a, bb, acc[cf], 0, 0, 0);
    }
  }
  for(int cf = 0; cf < 16; cf++){
    int d = cf * 16 + rl;
    float bpd = bp[d];
    for(int r = 0; r < 4; r++){
      int tl = w * 16 + kg * 4 + r;
      out[(size_t)(g0 + tl) * 256 + d] = acc[cf][r] + bpd;
    }
  }
}

extern "C" void kernel_launch(void* const* d_in, const int* in_sizes, int n_in,
                              void* d_out, int out_size, void* d_ws, size_t ws_size,
                              hipStream_t stream)
{
  const float* x  = (const float*)d_in[0];
  const float* ab = (const float*)d_in[1];
  const float* Wq = (const float*)d_in[2];
  const float* bq = (const float*)d_in[3];
  const float* Wk = (const float*)d_in[4];
  const float* bk = (const float*)d_in[5];
  const float* Wv = (const float*)d_in[6];
  const float* bv = (const float*)d_in[7];
  const float* Wp = (const float*)d_in[8];
  const float* bp = (const float*)d_in[9];
  float* out = (float*)d_out;

  char* ws = (char*)d_ws;
  unsigned short* Qsigb = (unsigned short*)(ws);            //  0.0 MB (4.2 bf16)
  unsigned short* Ktb   = (unsigned short*)(ws + 8388608);  //  8.4 MB (4.2 bf16) -> Yt later
  unsigned short* Vtb   = (unsigned short*)(ws + 12582912); // 12.6 MB (4.2 bf16)
  unsigned short* Mt    = (unsigned short*)(ws + 16777216); // 16.8 MB (8.4 bf16)
  unsigned short* eab   = (unsigned short*)(ws + 25165824); // 25.2 MB (67.1 bf16)
  unsigned short* Yt    = (unsigned short*)(ws + 8388608);  // reuse Ktb slot (4.2)

  qkv_kernel<<<dim3(256, 3), 256, 0, stream>>>(x, Wq, bq, Wk, bk, Wv, bv, Qsigb, Ktb, Vtb);
  colsm_kernel<<<256, 256, 0, stream>>>(Ktb, Vtb, Mt);
  softexp_kernel<<<16384, 256, 0, stream>>>(ab, eab);
  aft_gemm10<<<512, 256, 0, stream>>>(eab, Mt, Qsigb, Yt);
  outproj_kernel<<<256, 256, 0, stream>>>(Yt, Wp, bp, out);
}

// Round 14
// 96.674 us; speedup vs baseline: 1.6121x; 1.6121x over previous
//
#include <hip/hip_runtime.h>
#include <hip/hip_bf16.h>

#define B_ 8
#define T_ 2048
#define D_ 256
#define H_ 128

typedef float f32x4 __attribute__((ext_vector_type(4)));
typedef short bf16x8 __attribute__((ext_vector_type(8)));
typedef unsigned short u16x8 __attribute__((ext_vector_type(8)));

__device__ __forceinline__ unsigned short f2bf(float f){
  union { float f; unsigned u; } v; v.f = f;
  unsigned u = v.u;
  unsigned r = (u + 0x7FFFu + ((u >> 16) & 1u)) >> 16;
  return (unsigned short)r;
}

__device__ __forceinline__ float bf2f(unsigned short us){
  union { unsigned u; float f; } v; v.u = ((unsigned)us) << 16; return v.f;
}

#define GLL16(g, l) __builtin_amdgcn_global_load_lds( \
    (const __attribute__((address_space(1))) void*)(g), \
    (__attribute__((address_space(3))) void*)(l), 16, 0, 0)

// 256-thread (4-wave) block reduce; sbuf must be float[4]
__device__ __forceinline__ float blk_reduce(float v, bool is_max, float* sbuf){
  for(int o = 32; o > 0; o >>= 1){
    float t = __shfl_xor(v, o);
    v = is_max ? fmaxf(v, t) : (v + t);
  }
  int w = threadIdx.x >> 6;
  __syncthreads();
  if((threadIdx.x & 63) == 0) sbuf[w] = v;
  __syncthreads();
  float r = sbuf[0];
  for(int i = 1; i < 4; i++) r = is_max ? fmaxf(r, sbuf[i]) : (r + sbuf[i]);
  return r;
}

// ---------------------------------------------------------------------------
// Kernel 1: QKV projection (R7-verified structure). grid (256 rowtiles, 3
// mats), 256 threads.
// ---------------------------------------------------------------------------
__global__ __launch_bounds__(256) void qkv_kernel(
    const float* __restrict__ x,
    const float* __restrict__ Wq, const float* __restrict__ bq,
    const float* __restrict__ Wk, const float* __restrict__ bk,
    const float* __restrict__ Wv, const float* __restrict__ bv,
    unsigned short* __restrict__ Qsigb, unsigned short* __restrict__ Ktb,
    unsigned short* __restrict__ Vtb)
{
  const int mat = blockIdx.y;
  const int g0  = blockIdx.x * 64;
  const int tid = threadIdx.x;
  const float* W   = (mat == 0) ? Wq : (mat == 1) ? Wk : Wv;
  const float* bia = (mat == 0) ? bq : (mat == 1) ? bk : bv;

  __shared__ __align__(16) short As[64 * 32];
  __shared__ __align__(16) short Ws[128 * 32];
  __shared__ float tbuf[64][129];

  const int w = tid >> 6, lane = tid & 63, rl = lane & 15, kg = lane >> 4;
  f32x4 acc[8];
  for(int i = 0; i < 8; i++) acc[i] = (f32x4){0.f, 0.f, 0.f, 0.f};

  const int c = tid & 31, r8 = tid >> 5;
  for(int kk = 0; kk < 256; kk += 32){
    __syncthreads();
    for(int p = 0; p < 8; p++){
      int rr = r8 + p * 8;
      As[rr * 32 + c] = (short)f2bf(x[(size_t)(g0 + rr) * 256 + kk + c]);
    }
    for(int p = 0; p < 16; p++){
      int hh = r8 + p * 8;
      Ws[hh * 32 + c] = (short)f2bf(W[(size_t)hh * 256 + kk + c]);
    }
    __syncthreads();
    bf16x8 a = *(const bf16x8*)&As[(w * 16 + rl) * 32 + kg * 8];
    for(int cf = 0; cf < 8; cf++){
      bf16x8 bb = *(const bf16x8*)&Ws[(cf * 16 + rl) * 32 + kg * 8];
      acc[cf] = __builtin_amdgcn_mfma_f32_16x16x32_bf16(a, bb, acc[cf], 0, 0, 0);
    }
  }

  const int b = g0 >> 11, t0 = g0 & 2047;
  if(mat == 0){
    for(int cf = 0; cf < 8; cf++){
      int h = cf * 16 + rl;
      float bh = bia[h];
      for(int r = 0; r < 4; r++){
        int tl = w * 16 + kg * 4 + r;
        float v = acc[cf][r] + bh;
        Qsigb[(size_t)(g0 + tl) * 128 + h] = f2bf(1.f / (1.f + __expf(-v)));
      }
    }
  } else {
    for(int cf = 0; cf < 8; cf++){
      int h = cf * 16 + rl;
      float bh = bia[h];
      for(int r = 0; r < 4; r++){
        int tl = w * 16 + kg * 4 + r;
        tbuf[tl][h] = acc[cf][r] + bh;
      }
    }
    __syncthreads();
    unsigned short* dst = (mat == 1) ? Ktb : Vtb;
    int h = tid >> 1, part = tid & 1;
    unsigned short* drow = dst + (size_t)(b * 128 + h) * 2048 + t0 + part * 32;
#pragma unroll
    for(int i = 0; i < 32; i += 8){
      u16x8 o;
#pragma unroll
      for(int j = 0; j < 8; j++) o[j] = f2bf(tbuf[part * 32 + i + j][h]);
      *(u16x8*)(drow + i) = o;
    }
  }
}

// ---------------------------------------------------------------------------
// Kernel 2: column softmax over time for K -> Mt rows 0..127 = bf16(eK*V),
// rows 128..255 = bf16(eK). Inputs bf16.
// ---------------------------------------------------------------------------
__global__ __launch_bounds__(256) void colsm_kernel(
    const unsigned short* __restrict__ Ktb, const unsigned short* __restrict__ Vtb,
    unsigned short* __restrict__ Mt)
{
  __shared__ float sbuf[4];
  const int b  = blockIdx.x >> 5;
  const int hg = blockIdx.x & 31;
  const int tid = threadIdx.x;
  for(int i = 0; i < 4; i++){
    int h = hg * 4 + i;
    const unsigned short* kr = Ktb + (size_t)(b * 128 + h) * 2048;
    const unsigned short* vr = Vtb + (size_t)(b * 128 + h) * 2048;
    u16x8 k8 = *(const u16x8*)(kr + tid * 8);
    u16x8 v8 = *(const u16x8*)(vr + tid * 8);
    float kf[8];
#pragma unroll
    for(int j = 0; j < 8; j++) kf[j] = bf2f(k8[j]);
    float m = kf[0];
#pragma unroll
    for(int j = 1; j < 8; j++) m = fmaxf(m, kf[j]);
    m = blk_reduce(m, true, sbuf);
    float s = 0.f;
#pragma unroll
    for(int j = 0; j < 8; j++) s += __expf(kf[j] - m);
    s = blk_reduce(s, false, sbuf);
    float iz = 1.f / s;
    u16x8 pv, pe;
#pragma unroll
    for(int j = 0; j < 8; j++){
      float e = __expf(__expf(kf[j] - m) * iz);
      pv[j] = f2bf(e * bf2f(v8[j]));
      pe[j] = f2bf(e);
    }
    *(u16x8*)(Mt + (size_t)(b * 256 + h) * 2048 + tid * 8) = pv;
    *(u16x8*)(Mt + (size_t)(b * 256 + 128 + h) * 2048 + tid * 8) = pe;
  }
}

// ---------------------------------------------------------------------------
// Kernel 3: fused row-softmax + exp -> bf16 eab. One row per block.
// ---------------------------------------------------------------------------
__global__ __launch_bounds__(256) void softexp_kernel(
    const float* __restrict__ ab, unsigned short* __restrict__ eab)
{
  __shared__ float sbuf[4];
  const size_t row = blockIdx.x;
  const float* r = ab + row * 2048;
  const int tid = threadIdx.x;
  float4 v0 = *(const float4*)(r + tid * 4);
  float4 v1 = *(const float4*)(r + tid * 4 + 1024);
  float m = fmaxf(fmaxf(fmaxf(v0.x, v0.y), fmaxf(v0.z, v0.w)),
                  fmaxf(fmaxf(v1.x, v1.y), fmaxf(v1.z, v1.w)));
  m = blk_reduce(m, true, sbuf);
  float e0x = __expf(v0.x - m), e0y = __expf(v0.y - m);
  float e0z = __expf(v0.z - m), e0w = __expf(v0.w - m);
  float e1x = __expf(v1.x - m), e1y = __expf(v1.y - m);
  float e1z = __expf(v1.z - m), e1w = __expf(v1.w - m);
  float s = e0x + e0y + e0z + e0w + e1x + e1y + e1z + e1w;
  s = blk_reduce(s, false, sbuf);
  float iz = 1.f / s;
  ushort4 o;
  o.x = f2bf(__expf(e0x * iz)); o.y = f2bf(__expf(e0y * iz));
  o.z = f2bf(__expf(e0z * iz)); o.w = f2bf(__expf(e0w * iz));
  *(ushort4*)(eab + row * 2048 + tid * 4) = o;
  o.x = f2bf(__expf(e1x * iz)); o.y = f2bf(__expf(e1y * iz));
  o.z = f2bf(__expf(e1z * iz)); o.w = f2bf(__expf(e1w * iz));
  *(ushort4*)(eab + row * 2048 + tid * 4 + 1024) = o;
}

// ---------------------------------------------------------------------------
// Kernel 4: bf16 GEMM — gemm4 geometry + register fragment double-buffer.
// Block tile: 64 rows x (64 num + 64 den cols), BK=64, 4 waves (wave 32x64).
// grid 512 = 8 XCD-pinned batches x 32 rt x 2 hb; LDS 48 KB, lb(256,3)
// -> 3 blocks/CU.
// Iter t: stage(t+2) -> vmcnt(6) -> barrier -> ds_read frags(t+1) (no wait)
//   -> 16 MFMA on frags(t) [hides ds_read latency] -> lgkmcnt(0) -> barrier.
// ---------------------------------------------------------------------------
__global__ __launch_bounds__(256, 3) void aft_gemm11(
    const unsigned short* __restrict__ eab,
    const unsigned short* __restrict__ Mt,
    const unsigned short* __restrict__ Qsigb,
    unsigned short* __restrict__ Yt)
{
  __shared__ __align__(16) unsigned short As2[2][64 * 64];   // 16 KB
  __shared__ __align__(16) unsigned short Bs2[2][128 * 64];  // 32 KB

  const int bid = blockIdx.x;
  const int b   = bid & 7;
  const int idx = bid >> 3;          // 0..63
  const int rt  = idx >> 1;          // 0..31
  const int hb  = idx & 1;
  const int t0  = rt * 64;
  const int h0  = hb * 64;

  const int tid = threadIdx.x;
  const int w = tid >> 6, lane = tid & 63;
  const int rl = lane & 15, kg = lane >> 4;
  const int wr = w >> 1, wc = w & 1;

  // staging geometry (rule #21: linear LDS dest, inverse-swizzled global src)
  const int lr = lane >> 3;          // 0..7
  const int cc = (lane & 7) ^ lr;    // chunk of 8 shorts

  const size_t rowbase = (size_t)b * 2048 + t0;
  const unsigned short* a_src = eab + (rowbase + (size_t)(w * 16 + lr)) * 2048 + cc * 8;
  const int mtrow = (w < 2) ? (h0 + w * 32 + lr) : (128 + h0 + (w - 2) * 32 + lr);
  const unsigned short* b_src = Mt + ((size_t)b * 256 + mtrow) * 2048 + cc * 8;

  f32x4 acc[2][4];
#pragma unroll
  for(int i = 0; i < 2; i++)
#pragma unroll
    for(int j = 0; j < 4; j++) acc[i][j] = (f32x4){0.f, 0.f, 0.f, 0.f};

  auto stage = [&](int buf, int t){
#pragma unroll
    for(int i = 0; i < 2; i++)
      GLL16(a_src + (size_t)i * 8 * 2048 + t * 64, &As2[buf][(w * 16 + i * 8) * 64]);
#pragma unroll
    for(int i = 0; i < 4; i++)
      GLL16(b_src + (size_t)i * 8 * 2048 + t * 64, &Bs2[buf][(w * 32 + i * 8) * 64]);
  };

  const int rx = rl & 7;

  // ds_read frags of LDS buffer `cur` into named bank
  #define DSREAD(BK_, cur) do { \
    _Pragma("unroll") \
    for(int ks = 0; ks < 2; ++ks){ \
      const int slot = ((ks * 4 + kg) ^ rx) * 8; \
      BK_##A[ks][0] = *(const bf16x8*)&As2[cur][(wr * 32 + rl) * 64 + slot]; \
      BK_##A[ks][1] = *(const bf16x8*)&As2[cur][(wr * 32 + 16 + rl) * 64 + slot]; \
      _Pragma("unroll") \
      for(int cf = 0; cf < 4; ++cf){ \
        const int brow = ((cf < 2) ? (wc * 32 + cf * 16) \
                                   : (64 + wc * 32 + (cf - 2) * 16)) + rl; \
        BK_##B[ks][cf] = *(const bf16x8*)&Bs2[cur][brow * 64 + slot]; \
      } \
    } \
  } while(0)

  #define MM(BK_) do { \
    __builtin_amdgcn_s_setprio(1); \
    _Pragma("unroll") \
    for(int ks = 0; ks < 2; ++ks) \
      _Pragma("unroll") \
      for(int cf = 0; cf < 4; ++cf){ \
        acc[0][cf] = __builtin_amdgcn_mfma_f32_16x16x32_bf16(BK_##A[ks][0], BK_##B[ks][cf], acc[0][cf], 0, 0, 0); \
        acc[1][cf] = __builtin_amdgcn_mfma_f32_16x16x32_bf16(BK_##A[ks][1], BK_##B[ks][cf], acc[1][cf], 0, 0, 0); \
      } \
    __builtin_amdgcn_s_setprio(0); \
  } while(0)

  // Iter: consume CUR (frags of tile t), read NXT (frags of t+1).
  #define ITER(t, CUR, NXT) do { \
    if((t) < 30) stage((t) & 1, (t) + 2); \
    if((t) < 30) asm volatile("s_waitcnt vmcnt(6)" ::: "memory"); \
    else         asm volatile("s_waitcnt vmcnt(0)" ::: "memory"); \
    __builtin_amdgcn_s_barrier(); \
    asm volatile("" ::: "memory"); \
    DSREAD(NXT, ((t) + 1) & 1); \
    MM(CUR); \
    asm volatile("s_waitcnt lgkmcnt(0)" ::: "memory"); \
    __builtin_amdgcn_sched_barrier(0); \
    __builtin_amdgcn_s_barrier(); \
    asm volatile("" ::: "memory"); \
  } while(0)

  bf16x8 XA[2][2], XB[2][4], YA[2][2], YB[2][4];

  // prologue: fill both LDS buffers, preload frags(0) into bank X
  stage(0, 0);
  stage(1, 1);                       // 12 loads/lane outstanding
  asm volatile("s_waitcnt vmcnt(6)" ::: "memory");   // stage(0) landed
  __builtin_amdgcn_s_barrier();
  asm volatile("" ::: "memory");
  DSREAD(X, 0);
  asm volatile("s_waitcnt lgkmcnt(0)" ::: "memory");
  __builtin_amdgcn_sched_barrier(0);
  __builtin_amdgcn_s_barrier();      // all waves done reading buf0 (tile 0)
  asm volatile("" ::: "memory");

#pragma unroll 1
  for(int t = 0; t < 30; t += 2){
    ITER(t,     X, Y);
    ITER(t + 1, Y, X);
  }
  ITER(30, X, Y);                    // reads frags(31) into Y, MFMAs tile 30
  MM(Y);                             // tile 31

  #undef ITER
  #undef MM
  #undef DSREAD

#pragma unroll
  for(int rf = 0; rf < 2; ++rf)
#pragma unroll
    for(int cf = 0; cf < 2; ++cf){
      const int h = h0 + wc * 32 + cf * 16 + rl;
#pragma unroll
      for(int r = 0; r < 4; ++r){
        const int tl = wr * 32 + rf * 16 + kg * 4 + r;
        const size_t g = rowbase + tl;
        float num = acc[rf][cf][r], den = acc[rf][cf + 2][r];
        float q = bf2f(Qsigb[g * 128 + h]);
        Yt[g * 128 + h] = f2bf(q * num / den);
      }
    }
}

// ---------------------------------------------------------------------------
// Kernel 5: output projection out = Yt @ Wp^T + bp. grid = 256, 256 threads.
// ---------------------------------------------------------------------------
__global__ __launch_bounds__(256) void outproj_kernel(
    const unsigned short* __restrict__ Yt, const float* __restrict__ Wp,
    const float* __restrict__ bp, float* __restrict__ out)
{
  __shared__ __align__(16) short As[64 * 32];
  __shared__ __align__(16) short Bs[256 * 32];
  const int g0 = blockIdx.x * 64;
  const int tid = threadIdx.x;
  const int w = tid >> 6, lane = tid & 63, rl = lane & 15, kg = lane >> 4;
  f32x4 acc[16];
  for(int i = 0; i < 16; i++) acc[i] = (f32x4){0.f, 0.f, 0.f, 0.f};

  const int ar = tid >> 2, apart = tid & 3;
  const int c = tid & 31, dr = tid >> 5;
  for(int k = 0; k < 128; k += 32){
    __syncthreads();
    *(uint4*)&As[ar * 32 + apart * 8] =
        *(const uint4*)(Yt + (size_t)(g0 + ar) * 128 + k + apart * 8);
    for(int p = 0; p < 32; p++){
      int d = dr + p * 8;
      Bs[d * 32 + c] = (short)f2bf(Wp[(size_t)d * 128 + k + c]);
    }
    __syncthreads();
    bf16x8 a = *(const bf16x8*)&As[(w * 16 + rl) * 32 + kg * 8];
    for(int cf = 0; cf < 16; cf++){
      bf16x8 bb = *(const bf16x8*)&Bs[(cf * 16 + rl) * 32 + kg * 8];
      acc[cf] = __builtin_amdgcn_mfma_f32_16x16x32_bf16(a, bb, acc[cf], 0, 0, 0);
    }
  }
  for(int cf = 0; cf < 16; cf++){
    int d = cf * 16 + rl;
    float bpd = bp[d];
    for(int r = 0; r < 4; r++){
      int tl = w * 16 + kg * 4 + r;
      out[(size_t)(g0 + tl) * 256 + d] = acc[cf][r] + bpd;
    }
  }
}

extern "C" void kernel_launch(void* const* d_in, const int* in_sizes, int n_in,
                              void* d_out, int out_size, void* d_ws, size_t ws_size,
                              hipStream_t stream)
{
  const float* x  = (const float*)d_in[0];
  const float* ab = (const float*)d_in[1];
  const float* Wq = (const float*)d_in[2];
  const float* bq = (const float*)d_in[3];
  const float* Wk = (const float*)d_in[4];
  const float* bk = (const float*)d_in[5];
  const float* Wv = (const float*)d_in[6];
  const float* bv = (const float*)d_in[7];
  const float* Wp = (const float*)d_in[8];
  const float* bp = (const float*)d_in[9];
  float* out = (float*)d_out;

  char* ws = (char*)d_ws;
  unsigned short* Qsigb = (unsigned short*)(ws);            //  0.0 MB (4.2 bf16)
  unsigned short* Ktb   = (unsigned short*)(ws + 8388608);  //  8.4 MB (4.2 bf16) -> Yt later
  unsigned short* Vtb   = (unsigned short*)(ws + 12582912); // 12.6 MB (4.2 bf16)
  unsigned short* Mt    = (unsigned short*)(ws + 16777216); // 16.8 MB (8.4 bf16)
  unsigned short* eab   = (unsigned short*)(ws + 25165824); // 25.2 MB (67.1 bf16)
  unsigned short* Yt    = (unsigned short*)(ws + 8388608);  // reuse Ktb slot (4.2)

  qkv_kernel<<<dim3(256, 3), 256, 0, stream>>>(x, Wq, bq, Wk, bk, Wv, bv, Qsigb, Ktb, Vtb);
  colsm_kernel<<<256, 256, 0, stream>>>(Ktb, Vtb, Mt);
  softexp_kernel<<<16384, 256, 0, stream>>>(ab, eab);
  aft_gemm11<<<512, 256, 0, stream>>>(eab, Mt, Qsigb, Yt);
  outproj_kernel<<<256, 256, 0, stream>>>(Yt, Wp, bp, out);
}

// Round 15
// 87.011 us; speedup vs baseline: 1.7911x; 1.1111x over previous
//
#include <hip/hip_runtime.h>
#include <hip/hip_bf16.h>

#define B_ 8
#define T_ 2048
#define D_ 256
#define H_ 128

typedef float f32x4 __attribute__((ext_vector_type(4)));
typedef short bf16x8 __attribute__((ext_vector_type(8)));
typedef unsigned short u16x8 __attribute__((ext_vector_type(8)));

__device__ __forceinline__ unsigned short f2bf(float f){
  union { float f; unsigned u; } v; v.f = f;
  unsigned u = v.u;
  unsigned r = (u + 0x7FFFu + ((u >> 16) & 1u)) >> 16;
  return (unsigned short)r;
}

__device__ __forceinline__ float bf2f(unsigned short us){
  union { unsigned u; float f; } v; v.u = ((unsigned)us) << 16; return v.f;
}

#define GLL16(g, l) __builtin_amdgcn_global_load_lds( \
    (const __attribute__((address_space(1))) void*)(g), \
    (__attribute__((address_space(3))) void*)(l), 16, 0, 0)

// 256-thread (4-wave) block reduce; sbuf must be float[4]
__device__ __forceinline__ float blk_reduce(float v, bool is_max, float* sbuf){
  for(int o = 32; o > 0; o >>= 1){
    float t = __shfl_xor(v, o);
    v = is_max ? fmaxf(v, t) : (v + t);
  }
  int w = threadIdx.x >> 6;
  __syncthreads();
  if((threadIdx.x & 63) == 0) sbuf[w] = v;
  __syncthreads();
  float r = sbuf[0];
  for(int i = 1; i < 4; i++) r = is_max ? fmaxf(r, sbuf[i]) : (r + sbuf[i]);
  return r;
}

// ---------------------------------------------------------------------------
// Kernel 1: QKV projection (R7-verified structure). grid (256 rowtiles, 3
// mats), 256 threads.
// ---------------------------------------------------------------------------
__global__ __launch_bounds__(256) void qkv_kernel(
    const float* __restrict__ x,
    const float* __restrict__ Wq, const float* __restrict__ bq,
    const float* __restrict__ Wk, const float* __restrict__ bk,
    const float* __restrict__ Wv, const float* __restrict__ bv,
    unsigned short* __restrict__ Qsigb, unsigned short* __restrict__ Ktb,
    unsigned short* __restrict__ Vtb)
{
  const int mat = blockIdx.y;
  const int g0  = blockIdx.x * 64;
  const int tid = threadIdx.x;
  const float* W   = (mat == 0) ? Wq : (mat == 1) ? Wk : Wv;
  const float* bia = (mat == 0) ? bq : (mat == 1) ? bk : bv;

  __shared__ __align__(16) short As[64 * 32];
  __shared__ __align__(16) short Ws[128 * 32];
  __shared__ float tbuf[64][129];

  const int w = tid >> 6, lane = tid & 63, rl = lane & 15, kg = lane >> 4;
  f32x4 acc[8];
  for(int i = 0; i < 8; i++) acc[i] = (f32x4){0.f, 0.f, 0.f, 0.f};

  const int c = tid & 31, r8 = tid >> 5;
  for(int kk = 0; kk < 256; kk += 32){
    __syncthreads();
    for(int p = 0; p < 8; p++){
      int rr = r8 + p * 8;
      As[rr * 32 + c] = (short)f2bf(x[(size_t)(g0 + rr) * 256 + kk + c]);
    }
    for(int p = 0; p < 16; p++){
      int hh = r8 + p * 8;
      Ws[hh * 32 + c] = (short)f2bf(W[(size_t)hh * 256 + kk + c]);
    }
    __syncthreads();
    bf16x8 a = *(const bf16x8*)&As[(w * 16 + rl) * 32 + kg * 8];
    for(int cf = 0; cf < 8; cf++){
      bf16x8 bb = *(const bf16x8*)&Ws[(cf * 16 + rl) * 32 + kg * 8];
      acc[cf] = __builtin_amdgcn_mfma_f32_16x16x32_bf16(a, bb, acc[cf], 0, 0, 0);
    }
  }

  const int b = g0 >> 11, t0 = g0 & 2047;
  if(mat == 0){
    for(int cf = 0; cf < 8; cf++){
      int h = cf * 16 + rl;
      float bh = bia[h];
      for(int r = 0; r < 4; r++){
        int tl = w * 16 + kg * 4 + r;
        float v = acc[cf][r] + bh;
        Qsigb[(size_t)(g0 + tl) * 128 + h] = f2bf(1.f / (1.f + __expf(-v)));
      }
    }
  } else {
    for(int cf = 0; cf < 8; cf++){
      int h = cf * 16 + rl;
      float bh = bia[h];
      for(int r = 0; r < 4; r++){
        int tl = w * 16 + kg * 4 + r;
        tbuf[tl][h] = acc[cf][r] + bh;
      }
    }
    __syncthreads();
    unsigned short* dst = (mat == 1) ? Ktb : Vtb;
    int h = tid >> 1, part = tid & 1;
    unsigned short* drow = dst + (size_t)(b * 128 + h) * 2048 + t0 + part * 32;
#pragma unroll
    for(int i = 0; i < 32; i += 8){
      u16x8 o;
#pragma unroll
      for(int j = 0; j < 8; j++) o[j] = f2bf(tbuf[part * 32 + i + j][h]);
      *(u16x8*)(drow + i) = o;
    }
  }
}

// ---------------------------------------------------------------------------
// Kernel 2 (fat, independent roles, both tiny-LDS / full-occupancy):
//   blocks [0,256):        colsm — column softmax of K -> Mt (bf16)
//   blocks [256, 16640):   softexp — row softmax+exp of ab -> eab (bf16)
// colsm's ~3 us hides inside softexp's BW-bound stream.
// ---------------------------------------------------------------------------
__global__ __launch_bounds__(256) void se_cs_kernel(
    const float* __restrict__ ab, unsigned short* __restrict__ eab,
    const unsigned short* __restrict__ Ktb, const unsigned short* __restrict__ Vtb,
    unsigned short* __restrict__ Mt)
{
  __shared__ float sbuf[4];
  const int tid = threadIdx.x;

  if(blockIdx.x < 256){
    // ---- colsm role ----
    const int b  = blockIdx.x >> 5;
    const int hg = blockIdx.x & 31;
    for(int i = 0; i < 4; i++){
      int h = hg * 4 + i;
      const unsigned short* kr = Ktb + (size_t)(b * 128 + h) * 2048;
      const unsigned short* vr = Vtb + (size_t)(b * 128 + h) * 2048;
      u16x8 k8 = *(const u16x8*)(kr + tid * 8);
      u16x8 v8 = *(const u16x8*)(vr + tid * 8);
      float kf[8];
#pragma unroll
      for(int j = 0; j < 8; j++) kf[j] = bf2f(k8[j]);
      float m = kf[0];
#pragma unroll
      for(int j = 1; j < 8; j++) m = fmaxf(m, kf[j]);
      m = blk_reduce(m, true, sbuf);
      float s = 0.f;
#pragma unroll
      for(int j = 0; j < 8; j++) s += __expf(kf[j] - m);
      s = blk_reduce(s, false, sbuf);
      float iz = 1.f / s;
      u16x8 pv, pe;
#pragma unroll
      for(int j = 0; j < 8; j++){
        float e = __expf(__expf(kf[j] - m) * iz);
        pv[j] = f2bf(e * bf2f(v8[j]));
        pe[j] = f2bf(e);
      }
      *(u16x8*)(Mt + (size_t)(b * 256 + h) * 2048 + tid * 8) = pv;
      *(u16x8*)(Mt + (size_t)(b * 256 + 128 + h) * 2048 + tid * 8) = pe;
    }
    return;
  }

  // ---- softexp role ----
  const size_t row = blockIdx.x - 256;
  const float* r = ab + row * 2048;
  float4 v0 = *(const float4*)(r + tid * 4);
  float4 v1 = *(const float4*)(r + tid * 4 + 1024);
  float m = fmaxf(fmaxf(fmaxf(v0.x, v0.y), fmaxf(v0.z, v0.w)),
                  fmaxf(fmaxf(v1.x, v1.y), fmaxf(v1.z, v1.w)));
  m = blk_reduce(m, true, sbuf);
  float e0x = __expf(v0.x - m), e0y = __expf(v0.y - m);
  float e0z = __expf(v0.z - m), e0w = __expf(v0.w - m);
  float e1x = __expf(v1.x - m), e1y = __expf(v1.y - m);
  float e1z = __expf(v1.z - m), e1w = __expf(v1.w - m);
  float s = e0x + e0y + e0z + e0w + e1x + e1y + e1z + e1w;
  s = blk_reduce(s, false, sbuf);
  float iz = 1.f / s;
  ushort4 o;
  o.x = f2bf(__expf(e0x * iz)); o.y = f2bf(__expf(e0y * iz));
  o.z = f2bf(__expf(e0z * iz)); o.w = f2bf(__expf(e0w * iz));
  *(ushort4*)(eab + row * 2048 + tid * 4) = o;
  o.x = f2bf(__expf(e1x * iz)); o.y = f2bf(__expf(e1y * iz));
  o.z = f2bf(__expf(e1z * iz)); o.w = f2bf(__expf(e1w * iz));
  *(ushort4*)(eab + row * 2048 + tid * 4 + 1024) = o;
}

// ---------------------------------------------------------------------------
// Kernel 3: bf16 GEMM — R11's verified aft_gemm4 (best-evidence variant).
// Block tile: 64 rows x (64 num + 64 den cols), BK=64, 4 waves (wave 32x64).
// grid 512 = 8 XCD-pinned batches x 32 rt x 2 hb; LDS 48 KB -> 2 blk/CU.
// Counted vmcnt(6), double-barrier per K-step. Qsig read as bf16.
// ---------------------------------------------------------------------------
__global__ __launch_bounds__(256) void aft_gemm4(
    const unsigned short* __restrict__ eab,
    const unsigned short* __restrict__ Mt,
    const unsigned short* __restrict__ Qsigb,
    unsigned short* __restrict__ Yt)
{
  __shared__ __align__(16) unsigned short As2[2][64 * 64];   // 16 KB
  __shared__ __align__(16) unsigned short Bs2[2][128 * 64];  // 32 KB

  const int bid = blockIdx.x;
  const int b   = bid & 7;
  const int idx = bid >> 3;          // 0..63
  const int rt  = idx >> 1;          // 0..31
  const int hb  = idx & 1;           // 0..1
  const int t0  = rt * 64;
  const int h0  = hb * 64;

  const int tid = threadIdx.x;
  const int w = tid >> 6, lane = tid & 63;
  const int rl = lane & 15, kg = lane >> 4;
  const int wr = w >> 1, wc = w & 1;

  // staging geometry (rule #21: linear LDS dest, inverse-swizzled global src)
  const int lr = lane >> 3;          // 0..7
  const int cc = (lane & 7) ^ lr;    // chunk of 8 shorts

  const size_t rowbase = (size_t)b * 2048 + t0;
  const unsigned short* a_src = eab + (rowbase + (size_t)(w * 16 + lr)) * 2048 + cc * 8;
  const int mtrow = (w < 2) ? (h0 + w * 32 + lr) : (128 + h0 + (w - 2) * 32 + lr);
  const unsigned short* b_src = Mt + ((size_t)b * 256 + mtrow) * 2048 + cc * 8;

  f32x4 acc[2][4];
#pragma unroll
  for(int i = 0; i < 2; i++)
#pragma unroll
    for(int j = 0; j < 4; j++) acc[i][j] = (f32x4){0.f, 0.f, 0.f, 0.f};

  auto stage = [&](int buf, int t){
#pragma unroll
    for(int i = 0; i < 2; i++)
      GLL16(a_src + (size_t)i * 8 * 2048 + t * 64, &As2[buf][(w * 16 + i * 8) * 64]);
#pragma unroll
    for(int i = 0; i < 4; i++)
      GLL16(b_src + (size_t)i * 8 * 2048 + t * 64, &Bs2[buf][(w * 32 + i * 8) * 64]);
  };

  const int rx = rl & 7;
  stage(0, 0);
  stage(1, 1);                       // 12 loads/lane outstanding

  for(int t = 0; t < 32; ++t){
    const int cur = t & 1;
    if(t < 31) asm volatile("s_waitcnt vmcnt(6)" ::: "memory");  // stage(t) landed
    else       asm volatile("s_waitcnt vmcnt(0)" ::: "memory");
    __builtin_amdgcn_s_barrier();     // buf[cur] visible to all waves
    asm volatile("" ::: "memory");

    // ds_read all 12 fragments of this K-tile into registers
    bf16x8 af[2][2], bfr[2][4];
#pragma unroll
    for(int ks = 0; ks < 2; ++ks){
      const int slot = ((ks * 4 + kg) ^ rx) * 8;
      af[ks][0] = *(const bf16x8*)&As2[cur][(wr * 32 + rl) * 64 + slot];
      af[ks][1] = *(const bf16x8*)&As2[cur][(wr * 32 + 16 + rl) * 64 + slot];
#pragma unroll
      for(int cf = 0; cf < 4; ++cf){
        const int brow = ((cf < 2) ? (wc * 32 + cf * 16)
                                   : (64 + wc * 32 + (cf - 2) * 16)) + rl;
        bfr[ks][cf] = *(const bf16x8*)&Bs2[cur][brow * 64 + slot];
      }
    }
    asm volatile("s_waitcnt lgkmcnt(0)" ::: "memory");
    __builtin_amdgcn_sched_barrier(0);   // rule #18: pin MFMA below the wait
    __builtin_amdgcn_s_barrier();        // all waves done READING buf[cur]
    asm volatile("" ::: "memory");

    if(t < 30) stage(cur, t + 2);        // refill the buffer we just consumed

    __builtin_amdgcn_s_setprio(1);
#pragma unroll
    for(int ks = 0; ks < 2; ++ks)
#pragma unroll
      for(int cf = 0; cf < 4; ++cf){
        acc[0][cf] = __builtin_amdgcn_mfma_f32_16x16x32_bf16(af[ks][0], bfr[ks][cf], acc[0][cf], 0, 0, 0);
        acc[1][cf] = __builtin_amdgcn_mfma_f32_16x16x32_bf16(af[ks][1], bfr[ks][cf], acc[1][cf], 0, 0, 0);
      }
    __builtin_amdgcn_s_setprio(0);
  }

#pragma unroll
  for(int rf = 0; rf < 2; ++rf)
#pragma unroll
    for(int cf = 0; cf < 2; ++cf){
      const int h = h0 + wc * 32 + cf * 16 + rl;
#pragma unroll
      for(int r = 0; r < 4; ++r){
        const int tl = wr * 32 + rf * 16 + kg * 4 + r;
        const size_t g = rowbase + tl;
        float num = acc[rf][cf][r], den = acc[rf][cf + 2][r];
        float q = bf2f(Qsigb[g * 128 + h]);
        Yt[g * 128 + h] = f2bf(q * num / den);
      }
    }
}

// ---------------------------------------------------------------------------
// Kernel 4: output projection out = Yt @ Wp^T + bp. grid = 256, 256 threads.
// ---------------------------------------------------------------------------
__global__ __launch_bounds__(256) void outproj_kernel(
    const unsigned short* __restrict__ Yt, const float* __restrict__ Wp,
    const float* __restrict__ bp, float* __restrict__ out)
{
  __shared__ __align__(16) short As[64 * 32];
  __shared__ __align__(16) short Bs[256 * 32];
  const int g0 = blockIdx.x * 64;
  const int tid = threadIdx.x;
  const int w = tid >> 6, lane = tid & 63, rl = lane & 15, kg = lane >> 4;
  f32x4 acc[16];
  for(int i = 0; i < 16; i++) acc[i] = (f32x4){0.f, 0.f, 0.f, 0.f};

  const int ar = tid >> 2, apart = tid & 3;
  const int c = tid & 31, dr = tid >> 5;
  for(int k = 0; k < 128; k += 32){
    __syncthreads();
    *(uint4*)&As[ar * 32 + apart * 8] =
        *(const uint4*)(Yt + (size_t)(g0 + ar) * 128 + k + apart * 8);
    for(int p = 0; p < 32; p++){
      int d = dr + p * 8;
      Bs[d * 32 + c] = (short)f2bf(Wp[(size_t)d * 128 + k + c]);
    }
    __syncthreads();
    bf16x8 a = *(const bf16x8*)&As[(w * 16 + rl) * 32 + kg * 8];
    for(int cf = 0; cf < 16; cf++){
      bf16x8 bb = *(const bf16x8*)&Bs[(cf * 16 + rl) * 32 + kg * 8];
      acc[cf] = __builtin_amdgcn_mfma_f32_16x16x32_bf16(a, bb, acc[cf], 0, 0, 0);
    }
  }
  for(int cf = 0; cf < 16; cf++){
    int d = cf * 16 + rl;
    float bpd = bp[d];
    for(int r = 0; r < 4; r++){
      int tl = w * 16 + kg * 4 + r;
      out[(size_t)(g0 + tl) * 256 + d] = acc[cf][r] + bpd;
    }
  }
}

extern "C" void kernel_launch(void* const* d_in, const int* in_sizes, int n_in,
                              void* d_out, int out_size, void* d_ws, size_t ws_size,
                              hipStream_t stream)
{
  const float* x  = (const float*)d_in[0];
  const float* ab = (const float*)d_in[1];
  const float* Wq = (const float*)d_in[2];
  const float* bq = (const float*)d_in[3];
  const float* Wk = (const float*)d_in[4];
  const float* bk = (const float*)d_in[5];
  const float* Wv = (const float*)d_in[6];
  const float* bv = (const float*)d_in[7];
  const float* Wp = (const float*)d_in[8];
  const float* bp = (const float*)d_in[9];
  float* out = (float*)d_out;

  char* ws = (char*)d_ws;
  unsigned short* Qsigb = (unsigned short*)(ws);            //  0.0 MB (4.2 bf16)
  unsigned short* Ktb   = (unsigned short*)(ws + 8388608);  //  8.4 MB (4.2 bf16) -> Yt later
  unsigned short* Vtb   = (unsigned short*)(ws + 12582912); // 12.6 MB (4.2 bf16)
  unsigned short* Mt    = (unsigned short*)(ws + 16777216); // 16.8 MB (8.4 bf16)
  unsigned short* eab   = (unsigned short*)(ws + 25165824); // 25.2 MB (67.1 bf16)
  unsigned short* Yt    = (unsigned short*)(ws + 8388608);  // reuse Ktb slot (4.2)

  qkv_kernel<<<dim3(256, 3), 256, 0, stream>>>(x, Wq, bq, Wk, bk, Wv, bv, Qsigb, Ktb, Vtb);
  se_cs_kernel<<<16640, 256, 0, stream>>>(ab, eab, Ktb, Vtb, Mt);
  aft_gemm4<<<512, 256, 0, stream>>>(eab, Mt, Qsigb, Yt);
  outproj_kernel<<<256, 256, 0, stream>>>(Yt, Wp, bp, out);
}